// Round 4
// baseline (1920.119 us; speedup 1.0000x reference)
//
#include <hip/hip_runtime.h>

#define NNODES 50000
#define NREL   8
#define HID    64
#define NCLS   16
#define NEDGE  1600000
#define NTGT   8192
#define NBINS  (NNODES * NREL)
#define CHUNK  1024
#define NCHUNK ((NBINS + CHUNK - 1) / CHUNK)   // 391
#define CH2    4096                             // conv2 node chunk

__device__ __forceinline__ float elu1(float x) { return x > 0.f ? x : expm1f(x); }

__device__ __forceinline__ float w1at(const char* wl, int x) {
  return *(const float*)(wl + (((size_t)(unsigned)x) << 8));  // x = rel*NNODES+src, row = 256 B
}

// --- K1: per-(dst,rel) counts; epos[e] = slot within bin; 4 edges/thread -----
__global__ void count_kernel(const int* __restrict__ ei, const int* __restrict__ et,
                             int* __restrict__ cnt, int* __restrict__ epos) {
  int e4 = (blockIdx.x * blockDim.x + threadIdx.x) * 4;
  if (e4 >= NEDGE) return;
  int4 d = *(const int4*)(ei + NEDGE + e4);
  int4 r = *(const int4*)(et + e4);
  int4 p;
  p.x = atomicAdd(&cnt[d.x * NREL + r.x], 1);
  p.y = atomicAdd(&cnt[d.y * NREL + r.y], 1);
  p.z = atomicAdd(&cnt[d.z * NREL + r.z], 1);
  p.w = atomicAdd(&cnt[d.w * NREL + r.w], 1);
  *(int4*)(epos + e4) = p;
}

// --- K2a: per-chunk sums -----------------------------------------------------
__global__ void chunk_sum_kernel(const int* __restrict__ cnt, int* __restrict__ csum) {
  __shared__ int sw[4];
  int t = threadIdx.x, lane = t & 63, wid = t >> 6;
  int i = blockIdx.x * CHUNK + t * 4;
  int s = 0;
  if (i < NBINS) { int4 c = *(const int4*)(cnt + i); s = c.x + c.y + c.z + c.w; }
#pragma unroll
  for (int off = 32; off >= 1; off >>= 1) s += __shfl_xor(s, off);
  if (lane == 0) sw[wid] = s;
  __syncthreads();
  if (t == 0) csum[blockIdx.x] = sw[0] + sw[1] + sw[2] + sw[3];
}

// --- K2b: scan the 391 chunk sums (1 block) ---------------------------------
__global__ void scan_csum_kernel(const int* __restrict__ csum, int* __restrict__ cbase) {
  __shared__ int sw[8];
  int t = threadIdx.x, lane = t & 63, wid = t >> 6;  // 512 threads
  int v0 = (t < NCHUNK) ? csum[t] : 0;
  int v = v0;
#pragma unroll
  for (int off = 1; off < 64; off <<= 1) {
    int u = __shfl_up(v, off);
    if (lane >= off) v += u;
  }
  if (lane == 63) sw[wid] = v;
  __syncthreads();
  if (t == 0) {
    int run = 0;
#pragma unroll
    for (int j = 0; j < 8; ++j) { int x = sw[j]; sw[j] = run; run += x; }
  }
  __syncthreads();
  if (t < NCHUNK) cbase[t] = sw[wid] + (v - v0);
}

// --- K2c: per-chunk exclusive scan + base -> binptr --------------------------
__global__ void scan_write_kernel(const int* __restrict__ cnt, const int* __restrict__ cbase,
                                  int* __restrict__ binptr) {
  __shared__ int sw[4];
  int t = threadIdx.x, lane = t & 63, wid = t >> 6;
  int i = blockIdx.x * CHUNK + t * 4;
  int4 c = make_int4(0, 0, 0, 0);
  if (i < NBINS) c = *(const int4*)(cnt + i);
  int p0 = c.x, p1 = p0 + c.y, p2 = p1 + c.z, s = p2 + c.w;
  int v = s;
#pragma unroll
  for (int off = 1; off < 64; off <<= 1) {
    int u = __shfl_up(v, off);
    if (lane >= off) v += u;
  }
  if (lane == 63) sw[wid] = v;
  __syncthreads();
  if (t == 0) {
    int run = 0;
#pragma unroll
    for (int j = 0; j < 4; ++j) { int x = sw[j]; sw[j] = run; run += x; }
  }
  __syncthreads();
  if (i < NBINS) {
    int excl = cbase[blockIdx.x] + sw[wid] + (v - s);
    *(int4*)(binptr + i) = make_int4(excl, excl + p0, excl + p1, excl + p2);
  }
  if (blockIdx.x == 0 && t == 0) binptr[NBINS] = NEDGE;
}

// --- K3: scatter -> epo[pos] = {rel*NNODES+src, bits(1/cnt)}; 4 edges/thread -
__global__ void scatter_kernel(const int* __restrict__ ei, const int* __restrict__ et,
                               const int* __restrict__ epos, const int* __restrict__ binptr,
                               int2* __restrict__ epo) {
  int e4 = (blockIdx.x * blockDim.x + threadIdx.x) * 4;
  if (e4 >= NEDGE) return;
  int4 sv = *(const int4*)(ei + e4);
  int4 dv = *(const int4*)(ei + NEDGE + e4);
  int4 rv = *(const int4*)(et + e4);
  int4 pv = *(const int4*)(epos + e4);
  int srcs[4] = {sv.x, sv.y, sv.z, sv.w};
  int dsts[4] = {dv.x, dv.y, dv.z, dv.w};
  int rels[4] = {rv.x, rv.y, rv.z, rv.w};
  int poss[4] = {pv.x, pv.y, pv.z, pv.w};
#pragma unroll
  for (int j = 0; j < 4; ++j) {
    int bin = dsts[j] * NREL + rels[j];
    int b = binptr[bin];
    int c = binptr[bin + 1] - b;
    float sc = 1.0f / (float)c;  // c >= 1 (this edge is in the bin)
    epo[b + poss[j]] = make_int2(rels[j] * NNODES + srcs[j], __float_as_int(sc));
  }
}

// --- K4: conv1 — one wave per node, lane = channel; 8 gathers in flight ------
__global__ __launch_bounds__(256) void conv1_kernel(
    const int* __restrict__ binptr, const int2* __restrict__ epo,
    const float* __restrict__ w1, const float* __restrict__ root1,
    const float* __restrict__ bias1, float* __restrict__ h1) {
  int wave = blockIdx.x * (blockDim.x >> 6) + (threadIdx.x >> 6);
  if (wave >= NNODES) return;
  int lane = threadIdx.x & 63;
  int n = wave;
  const char* wl = (const char*)(w1 + lane);
  int b0 = binptr[n * NREL], b8 = binptr[n * NREL + NREL];
  float acc = 0.f;
  int e = b0;
  for (; e + 8 <= b8; e += 8) {
    int2 q0 = epo[e],     q1 = epo[e + 1], q2 = epo[e + 2], q3 = epo[e + 3];
    int2 q4 = epo[e + 4], q5 = epo[e + 5], q6 = epo[e + 6], q7 = epo[e + 7];
    float a0 = w1at(wl, q0.x), a1 = w1at(wl, q1.x), a2 = w1at(wl, q2.x), a3 = w1at(wl, q3.x);
    float a4 = w1at(wl, q4.x), a5 = w1at(wl, q5.x), a6 = w1at(wl, q6.x), a7 = w1at(wl, q7.x);
    acc = fmaf(a0, __int_as_float(q0.y), acc);
    acc = fmaf(a1, __int_as_float(q1.y), acc);
    acc = fmaf(a2, __int_as_float(q2.y), acc);
    acc = fmaf(a3, __int_as_float(q3.y), acc);
    acc = fmaf(a4, __int_as_float(q4.y), acc);
    acc = fmaf(a5, __int_as_float(q5.y), acc);
    acc = fmaf(a6, __int_as_float(q6.y), acc);
    acc = fmaf(a7, __int_as_float(q7.y), acc);
  }
  for (; e + 4 <= b8; e += 4) {
    int2 q0 = epo[e], q1 = epo[e + 1], q2 = epo[e + 2], q3 = epo[e + 3];
    float a0 = w1at(wl, q0.x), a1 = w1at(wl, q1.x), a2 = w1at(wl, q2.x), a3 = w1at(wl, q3.x);
    acc = fmaf(a0, __int_as_float(q0.y), acc);
    acc = fmaf(a1, __int_as_float(q1.y), acc);
    acc = fmaf(a2, __int_as_float(q2.y), acc);
    acc = fmaf(a3, __int_as_float(q3.y), acc);
  }
  for (; e < b8; ++e) {
    int2 q = epo[e];
    acc = fmaf(w1at(wl, q.x), __int_as_float(q.y), acc);
  }
  float v = acc + root1[(n << 6) + lane] + bias1[lane];
  h1[(n << 6) + lane] = elu1(v);
}

// --- K5a: conv2 aggregation — one wave per (node, rel) bin -------------------
__global__ __launch_bounds__(256) void conv2a_kernel(
    const int* __restrict__ binptr, const int2* __restrict__ epo,
    const float* __restrict__ h1, float* __restrict__ agg, int nodeBase) {
  int wv = blockIdx.x * 4 + (threadIdx.x >> 6);
  if (wv >= CH2 * NREL) return;
  int lane = threadIdx.x & 63;
  int ln = wv >> 3, r = wv & 7;
  int bin = (nodeBase + ln) * NREL + r;
  int bb = binptr[bin], ee = binptr[bin + 1];
  const float* hl = h1 + lane;
  int rbase = r * NNODES;
  float s = 0.f;
  int e = bb;
  for (; e + 4 <= ee; e += 4) {
    int2 q0 = epo[e], q1 = epo[e + 1], q2 = epo[e + 2], q3 = epo[e + 3];
    float a0 = hl[(q0.x - rbase) << 6];
    float a1 = hl[(q1.x - rbase) << 6];
    float a2 = hl[(q2.x - rbase) << 6];
    float a3 = hl[(q3.x - rbase) << 6];
    s += a0; s += a1; s += a2; s += a3;
  }
  for (; e < ee; ++e) s += hl[(epo[e].x - rbase) << 6];
  float out = 0.f;
  if (ee > bb) out = s * __int_as_float(epo[bb].y);  // per-bin mean (shared scale)
  agg[(wv << 6) + lane] = out;
}

// --- K5b: conv2 transform — wave per 4 nodes: o = sum_r agg_r@W2_r + h1@root2
__global__ __launch_bounds__(256) void conv2b_kernel(
    const float* __restrict__ agg, const float* __restrict__ h1,
    const float* __restrict__ w2, const float* __restrict__ root2,
    const float* __restrict__ bias2, float* __restrict__ h2, int nodeBase) {
  int wv = blockIdx.x * (blockDim.x >> 6) + (threadIdx.x >> 6);
  int lane = threadIdx.x & 63;
  int ln0 = wv * 4;
  if (ln0 >= CH2) return;
  float bz = bias2[lane];
  float o0 = bz, o1 = bz, o2 = bz, o3 = bz;
#pragma unroll
  for (int r = 0; r < NREL; ++r) {
    float a0 = agg[(((ln0 + 0) * NREL + r) << 6) + lane];
    float a1 = agg[(((ln0 + 1) * NREL + r) << 6) + lane];
    float a2 = agg[(((ln0 + 2) * NREL + r) << 6) + lane];
    float a3 = agg[(((ln0 + 3) * NREL + r) << 6) + lane];
    const float* w2r = w2 + (r << 12) + lane;
#pragma unroll
    for (int k = 0; k < HID; ++k) {
      float w = w2r[k << 6];
      o0 = fmaf(__shfl(a0, k), w, o0);
      o1 = fmaf(__shfl(a1, k), w, o1);
      o2 = fmaf(__shfl(a2, k), w, o2);
      o3 = fmaf(__shfl(a3, k), w, o3);
    }
  }
  int g0 = nodeBase + ln0;
  float v0 = h1[((g0 + 0) << 6) + lane];
  float v1 = h1[((g0 + 1) << 6) + lane];
  float v2 = h1[((g0 + 2) << 6) + lane];
  float v3 = h1[((g0 + 3) << 6) + lane];
#pragma unroll
  for (int k = 0; k < HID; ++k) {
    float w = root2[(k << 6) + lane];
    o0 = fmaf(__shfl(v0, k), w, o0);
    o1 = fmaf(__shfl(v1, k), w, o1);
    o2 = fmaf(__shfl(v2, k), w, o2);
    o3 = fmaf(__shfl(v3, k), w, o3);
  }
  h2[((g0 + 0) << 6) + lane] = elu1(o0);
  h2[((g0 + 1) << 6) + lane] = elu1(o1);
  h2[((g0 + 2) << 6) + lane] = elu1(o2);
  h2[((g0 + 3) << 6) + lane] = elu1(o3);
}

// --- K6: linear head ---------------------------------------------------------
__global__ void head_kernel(const float* __restrict__ h2, const float* __restrict__ lin_w,
                            const float* __restrict__ lin_b, float* __restrict__ out) {
  int t = blockIdx.x * blockDim.x + threadIdx.x;
  if (t >= NTGT * NCLS) return;
  int n = t >> 4, c = t & 15;
  float acc = lin_b[c];
#pragma unroll
  for (int k = 0; k < HID; ++k)
    acc = fmaf(h2[(n << 6) + k], lin_w[k * NCLS + c], acc);
  out[t] = acc;
}

extern "C" void kernel_launch(void* const* d_in, const int* in_sizes, int n_in,
                              void* d_out, int out_size, void* d_ws, size_t ws_size,
                              hipStream_t stream) {
  const int*   ei    = (const int*)d_in[0];
  const int*   et    = (const int*)d_in[1];
  const float* w1    = (const float*)d_in[3];
  const float* root1 = (const float*)d_in[4];
  const float* bias1 = (const float*)d_in[5];
  const float* w2    = (const float*)d_in[6];
  const float* root2 = (const float*)d_in[7];
  const float* bias2 = (const float*)d_in[8];
  const float* lin_w = (const float*)d_in[9];
  const float* lin_b = (const float*)d_in[10];
  float* out = (float*)d_out;

  // Workspace (~37.9 MB):
  //  A [0,12.8M): cnt(1.6)+epos(6.4) live until scatter; conv1 then writes h1 here
  //  B binptr/csum/cbase; C epo 12.8M; D h2 2.1M; E agg 8.4M (CH2=4096 chunk)
  char* ws = (char*)d_ws;
  float* h1     = (float*)ws;
  int*   cnt    = (int*)ws;
  int*   epos   = (int*)(ws + (size_t)NBINS * 4);
  char*  p      = ws + (size_t)NNODES * HID * 4;
  int*   binptr = (int*)p;  p += ((size_t)(NBINS + 1) * 4 + 255) & ~(size_t)255;
  int*   csum   = (int*)p;  p += ((size_t)NCHUNK * 4 + 255) & ~(size_t)255;
  int*   cbase  = (int*)p;  p += ((size_t)NCHUNK * 4 + 255) & ~(size_t)255;
  int2*  epo    = (int2*)p; p += (size_t)NEDGE * 8;
  float* h2     = (float*)p; p += (size_t)NTGT * HID * 4;
  float* agg    = (float*)p;

  hipMemsetAsync(cnt, 0, (size_t)NBINS * sizeof(int), stream);
  count_kernel<<<(NEDGE / 4 + 255) / 256, 256, 0, stream>>>(ei, et, cnt, epos);
  chunk_sum_kernel<<<NCHUNK, 256, 0, stream>>>(cnt, csum);
  scan_csum_kernel<<<1, 512, 0, stream>>>(csum, cbase);
  scan_write_kernel<<<NCHUNK, 256, 0, stream>>>(cnt, cbase, binptr);
  scatter_kernel<<<(NEDGE / 4 + 255) / 256, 256, 0, stream>>>(ei, et, epos, binptr, epo);
  conv1_kernel<<<(NNODES + 3) / 4, 256, 0, stream>>>(binptr, epo, w1, root1, bias1, h1);
  for (int c = 0; c < NTGT / CH2; ++c) {
    conv2a_kernel<<<(CH2 * NREL) / 4, 256, 0, stream>>>(binptr, epo, h1, agg, c * CH2);
    conv2b_kernel<<<(CH2 / 4 + 3) / 4, 256, 0, stream>>>(agg, h1, w2, root2, bias2, h2, c * CH2);
  }
  head_kernel<<<(NTGT * NCLS + 255) / 256, 256, 0, stream>>>(h2, lin_w, lin_b, out);
}

// Round 5
// 428.044 us; speedup vs baseline: 4.4858x; 4.4858x over previous
//
#include <hip/hip_runtime.h>

#define NNODES 50000
#define NREL   8
#define HID    64
#define NCLS   16
#define NEDGE  1600000
#define NTGT   8192
#define NBINS  (NNODES * NREL)
#define CHUNK  1024
#define NCHUNK ((NBINS + CHUNK - 1) / CHUNK)   // 391
#define CH2    4096                             // conv2 node chunk

__device__ __forceinline__ float elu1(float x) { return x > 0.f ? x : expm1f(x); }

// --- K1: per-(dst,rel) counts; epos[e] = slot within bin; 4 edges/thread -----
__global__ void count_kernel(const int* __restrict__ ei, const int* __restrict__ et,
                             int* __restrict__ cnt, int* __restrict__ epos) {
  int e4 = (blockIdx.x * blockDim.x + threadIdx.x) * 4;
  if (e4 >= NEDGE) return;
  int4 d = *(const int4*)(ei + NEDGE + e4);
  int4 r = *(const int4*)(et + e4);
  int4 p;
  p.x = atomicAdd(&cnt[d.x * NREL + r.x], 1);
  p.y = atomicAdd(&cnt[d.y * NREL + r.y], 1);
  p.z = atomicAdd(&cnt[d.z * NREL + r.z], 1);
  p.w = atomicAdd(&cnt[d.w * NREL + r.w], 1);
  *(int4*)(epos + e4) = p;
}

// --- K2a: per-chunk sums -----------------------------------------------------
__global__ void chunk_sum_kernel(const int* __restrict__ cnt, int* __restrict__ csum) {
  __shared__ int sw[4];
  int t = threadIdx.x, lane = t & 63, wid = t >> 6;
  int i = blockIdx.x * CHUNK + t * 4;
  int s = 0;
  if (i < NBINS) { int4 c = *(const int4*)(cnt + i); s = c.x + c.y + c.z + c.w; }
#pragma unroll
  for (int off = 32; off >= 1; off >>= 1) s += __shfl_xor(s, off);
  if (lane == 0) sw[wid] = s;
  __syncthreads();
  if (t == 0) csum[blockIdx.x] = sw[0] + sw[1] + sw[2] + sw[3];
}

// --- K2b: scan the 391 chunk sums (1 block) ---------------------------------
__global__ void scan_csum_kernel(const int* __restrict__ csum, int* __restrict__ cbase) {
  __shared__ int sw[8];
  int t = threadIdx.x, lane = t & 63, wid = t >> 6;  // 512 threads
  int v0 = (t < NCHUNK) ? csum[t] : 0;
  int v = v0;
#pragma unroll
  for (int off = 1; off < 64; off <<= 1) {
    int u = __shfl_up(v, off);
    if (lane >= off) v += u;
  }
  if (lane == 63) sw[wid] = v;
  __syncthreads();
  if (t == 0) {
    int run = 0;
#pragma unroll
    for (int j = 0; j < 8; ++j) { int x = sw[j]; sw[j] = run; run += x; }
  }
  __syncthreads();
  if (t < NCHUNK) cbase[t] = sw[wid] + (v - v0);
}

// --- K2c: per-chunk exclusive scan + base -> binptr --------------------------
__global__ void scan_write_kernel(const int* __restrict__ cnt, const int* __restrict__ cbase,
                                  int* __restrict__ binptr) {
  __shared__ int sw[4];
  int t = threadIdx.x, lane = t & 63, wid = t >> 6;
  int i = blockIdx.x * CHUNK + t * 4;
  int4 c = make_int4(0, 0, 0, 0);
  if (i < NBINS) c = *(const int4*)(cnt + i);
  int p0 = c.x, p1 = p0 + c.y, p2 = p1 + c.z, s = p2 + c.w;
  int v = s;
#pragma unroll
  for (int off = 1; off < 64; off <<= 1) {
    int u = __shfl_up(v, off);
    if (lane >= off) v += u;
  }
  if (lane == 63) sw[wid] = v;
  __syncthreads();
  if (t == 0) {
    int run = 0;
#pragma unroll
    for (int j = 0; j < 4; ++j) { int x = sw[j]; sw[j] = run; run += x; }
  }
  __syncthreads();
  if (i < NBINS) {
    int excl = cbase[blockIdx.x] + sw[wid] + (v - s);
    *(int4*)(binptr + i) = make_int4(excl, excl + p0, excl + p1, excl + p2);
  }
  if (blockIdx.x == 0 && t == 0) binptr[NBINS] = NEDGE;
}

// --- K3: scatter -> epo[pos] = {rel*NNODES+src, bits(1/cnt)}; 4 edges/thread -
__global__ void scatter_kernel(const int* __restrict__ ei, const int* __restrict__ et,
                               const int* __restrict__ epos, const int* __restrict__ binptr,
                               int2* __restrict__ epo) {
  int e4 = (blockIdx.x * blockDim.x + threadIdx.x) * 4;
  if (e4 >= NEDGE) return;
  int4 sv = *(const int4*)(ei + e4);
  int4 dv = *(const int4*)(ei + NEDGE + e4);
  int4 rv = *(const int4*)(et + e4);
  int4 pv = *(const int4*)(epos + e4);
  int srcs[4] = {sv.x, sv.y, sv.z, sv.w};
  int dsts[4] = {dv.x, dv.y, dv.z, dv.w};
  int rels[4] = {rv.x, rv.y, rv.z, rv.w};
  int poss[4] = {pv.x, pv.y, pv.z, pv.w};
#pragma unroll
  for (int j = 0; j < 4; ++j) {
    int bin = dsts[j] * NREL + rels[j];
    int b = binptr[bin];
    int c = binptr[bin + 1] - b;
    float sc = 1.0f / (float)c;  // c >= 1 (this edge is in the bin)
    epo[b + poss[j]] = make_int2(rels[j] * NNODES + srcs[j], __float_as_int(sc));
  }
}

// --- K4: conv1 — wave per node; batch 64 edges via one coalesced epo load,
//         broadcast (idx,scale) to SGPRs with readlane -> scalar-based gathers
__global__ __launch_bounds__(256) void conv1_kernel(
    const int* __restrict__ binptr, const int2* __restrict__ epo,
    const float* __restrict__ w1, const float* __restrict__ root1,
    const float* __restrict__ bias1, float* __restrict__ h1) {
  int wave = blockIdx.x * 4 + (threadIdx.x >> 6);
  if (wave >= NNODES) return;
  int lane = threadIdx.x & 63;
  int b0 = binptr[wave * NREL], b8 = binptr[wave * NREL + NREL];
  float acc0 = 0.f, acc1 = 0.f;
  for (int e = b0; e < b8; e += 64) {
    int mb = min(64, b8 - e);
    int2 q = epo[e + min(lane, mb - 1)];
    int j = 0;
#pragma unroll 8
    for (; j + 2 <= mb; j += 2) {
      int   i0 = __builtin_amdgcn_readlane(q.x, j);
      float s0 = __int_as_float(__builtin_amdgcn_readlane(q.y, j));
      int   i1 = __builtin_amdgcn_readlane(q.x, j + 1);
      float s1 = __int_as_float(__builtin_amdgcn_readlane(q.y, j + 1));
      acc0 = fmaf(w1[((size_t)(unsigned)i0 << 6) + lane], s0, acc0);
      acc1 = fmaf(w1[((size_t)(unsigned)i1 << 6) + lane], s1, acc1);
    }
    if (j < mb) {
      int   i0 = __builtin_amdgcn_readlane(q.x, j);
      float s0 = __int_as_float(__builtin_amdgcn_readlane(q.y, j));
      acc0 = fmaf(w1[((size_t)(unsigned)i0 << 6) + lane], s0, acc0);
    }
  }
  float v = acc0 + acc1 + root1[(wave << 6) + lane] + bias1[lane];
  h1[(wave << 6) + lane] = elu1(v);
}

// --- K5a: conv2 aggregation — wave per (node,rel) bin; readlane broadcast ----
__global__ __launch_bounds__(256) void conv2a_kernel(
    const int* __restrict__ binptr, const int2* __restrict__ epo,
    const float* __restrict__ h1, float* __restrict__ agg, int nodeBase) {
  int wv = blockIdx.x * 4 + (threadIdx.x >> 6);
  if (wv >= CH2 * NREL) return;
  int lane = threadIdx.x & 63;
  int r = wv & 7;
  int bin = (nodeBase + (wv >> 3)) * NREL + r;
  int bb = binptr[bin], ee = binptr[bin + 1];
  int rb = r * NNODES;
  float s0 = 0.f, s1 = 0.f;
  for (int e = bb; e < ee; e += 64) {
    int mb = min(64, ee - e);
    int2 q = epo[e + min(lane, mb - 1)];
    int j = 0;
#pragma unroll 4
    for (; j + 2 <= mb; j += 2) {
      int i0 = __builtin_amdgcn_readlane(q.x, j) - rb;
      int i1 = __builtin_amdgcn_readlane(q.x, j + 1) - rb;
      s0 += h1[((size_t)(unsigned)i0 << 6) + lane];
      s1 += h1[((size_t)(unsigned)i1 << 6) + lane];
    }
    if (j < mb) {
      int i0 = __builtin_amdgcn_readlane(q.x, j) - rb;
      s0 += h1[((size_t)(unsigned)i0 << 6) + lane];
    }
  }
  float out = (ee > bb) ? (s0 + s1) * (1.0f / (float)(ee - bb)) : 0.f;
  agg[((size_t)wv << 6) + lane] = out;
}

// --- K5b: conv2 transform — LDS-staged W (16 KB per relation), scalar A ------
__global__ __launch_bounds__(256, 4) void conv2b_kernel(
    const float* __restrict__ agg, const float* __restrict__ h1,
    const float* __restrict__ w2, const float* __restrict__ root2,
    const float* __restrict__ bias2, float* __restrict__ h2, int nodeBase) {
  __shared__ float sW[HID * HID];  // 16 KB
  int t = threadIdx.x, lane = t & 63, wid = t >> 6;
  int ln0 = blockIdx.x * 8 + wid * 2;  // 8 local nodes/block, 2 per wave
  float bz = bias2[lane];
  float o0 = bz, o1 = bz;
  for (int r = 0; r < NREL; ++r) {
    if (r) __syncthreads();
#pragma unroll
    for (int i = 0; i < 4; ++i)
      *(float4*)(sW + t * 4 + i * 1024) = *(const float4*)(w2 + (r << 12) + t * 4 + i * 1024);
    __syncthreads();
    const float* a0 = agg + (((size_t)((ln0 + 0) * NREL + r)) << 6);  // wave-uniform -> s_load
    const float* a1 = agg + (((size_t)((ln0 + 1) * NREL + r)) << 6);
#pragma unroll 16
    for (int k = 0; k < HID; ++k) {
      float w = sW[(k << 6) + lane];
      o0 = fmaf(a0[k], w, o0);
      o1 = fmaf(a1[k], w, o1);
    }
  }
  __syncthreads();
#pragma unroll
  for (int i = 0; i < 4; ++i)
    *(float4*)(sW + t * 4 + i * 1024) = *(const float4*)(root2 + t * 4 + i * 1024);
  __syncthreads();
  int g0 = nodeBase + ln0;
  const float* r0p = h1 + ((size_t)(g0 + 0) << 6);  // wave-uniform -> s_load
  const float* r1p = h1 + ((size_t)(g0 + 1) << 6);
#pragma unroll 16
  for (int k = 0; k < HID; ++k) {
    float w = sW[(k << 6) + lane];
    o0 = fmaf(r0p[k], w, o0);
    o1 = fmaf(r1p[k], w, o1);
  }
  h2[((size_t)(g0 + 0) << 6) + lane] = elu1(o0);
  h2[((size_t)(g0 + 1) << 6) + lane] = elu1(o1);
}

// --- K6: linear head ---------------------------------------------------------
__global__ void head_kernel(const float* __restrict__ h2, const float* __restrict__ lin_w,
                            const float* __restrict__ lin_b, float* __restrict__ out) {
  int t = blockIdx.x * blockDim.x + threadIdx.x;
  if (t >= NTGT * NCLS) return;
  int n = t >> 4, c = t & 15;
  float acc = lin_b[c];
#pragma unroll
  for (int k = 0; k < HID; ++k)
    acc = fmaf(h2[(n << 6) + k], lin_w[k * NCLS + c], acc);
  out[t] = acc;
}

extern "C" void kernel_launch(void* const* d_in, const int* in_sizes, int n_in,
                              void* d_out, int out_size, void* d_ws, size_t ws_size,
                              hipStream_t stream) {
  const int*   ei    = (const int*)d_in[0];
  const int*   et    = (const int*)d_in[1];
  const float* w1    = (const float*)d_in[3];
  const float* root1 = (const float*)d_in[4];
  const float* bias1 = (const float*)d_in[5];
  const float* w2    = (const float*)d_in[6];
  const float* root2 = (const float*)d_in[7];
  const float* bias2 = (const float*)d_in[8];
  const float* lin_w = (const float*)d_in[9];
  const float* lin_b = (const float*)d_in[10];
  float* out = (float*)d_out;

  // Workspace (~37.9 MB):
  //  A [0,12.8M): cnt(1.6)+epos(6.4) live until scatter; conv1 then writes h1 here
  //  B binptr/csum/cbase; C epo 12.8M; D h2 2.1M; E agg 8.4M (CH2=4096 chunk)
  char* ws = (char*)d_ws;
  float* h1     = (float*)ws;
  int*   cnt    = (int*)ws;
  int*   epos   = (int*)(ws + (size_t)NBINS * 4);
  char*  p      = ws + (size_t)NNODES * HID * 4;
  int*   binptr = (int*)p;  p += ((size_t)(NBINS + 1) * 4 + 255) & ~(size_t)255;
  int*   csum   = (int*)p;  p += ((size_t)NCHUNK * 4 + 255) & ~(size_t)255;
  int*   cbase  = (int*)p;  p += ((size_t)NCHUNK * 4 + 255) & ~(size_t)255;
  int2*  epo    = (int2*)p; p += (size_t)NEDGE * 8;
  float* h2     = (float*)p; p += (size_t)NTGT * HID * 4;
  float* agg    = (float*)p;

  hipMemsetAsync(cnt, 0, (size_t)NBINS * sizeof(int), stream);
  count_kernel<<<(NEDGE / 4 + 255) / 256, 256, 0, stream>>>(ei, et, cnt, epos);
  chunk_sum_kernel<<<NCHUNK, 256, 0, stream>>>(cnt, csum);
  scan_csum_kernel<<<1, 512, 0, stream>>>(csum, cbase);
  scan_write_kernel<<<NCHUNK, 256, 0, stream>>>(cnt, cbase, binptr);
  scatter_kernel<<<(NEDGE / 4 + 255) / 256, 256, 0, stream>>>(ei, et, epos, binptr, epo);
  conv1_kernel<<<(NNODES + 3) / 4, 256, 0, stream>>>(binptr, epo, w1, root1, bias1, h1);
  for (int c = 0; c < NTGT / CH2; ++c) {
    conv2a_kernel<<<(CH2 * NREL) / 4, 256, 0, stream>>>(binptr, epo, h1, agg, c * CH2);
    conv2b_kernel<<<CH2 / 8, 256, 0, stream>>>(agg, h1, w2, root2, bias2, h2, c * CH2);
  }
  head_kernel<<<(NTGT * NCLS + 255) / 256, 256, 0, stream>>>(h2, lin_w, lin_b, out);
}

// Round 6
// 402.062 us; speedup vs baseline: 4.7757x; 1.0646x over previous
//
#include <hip/hip_runtime.h>

#define NNODES 50000
#define NREL   8
#define HID    64
#define NCLS   16
#define NEDGE  1600000
#define NTGT   8192
#define NBINS  (NNODES * NREL)
#define CHUNK  1024
#define NCHUNK ((NBINS + CHUNK - 1) / CHUNK)   // 391

__device__ __forceinline__ float elu1(float x) { return x > 0.f ? x : expm1f(x); }

// --- K1: per-(dst,rel) counts; epos[e] = slot within bin; 4 edges/thread -----
__global__ void count_kernel(const int* __restrict__ ei, const int* __restrict__ et,
                             int* __restrict__ cnt, int* __restrict__ epos) {
  int e4 = (blockIdx.x * blockDim.x + threadIdx.x) * 4;
  if (e4 >= NEDGE) return;
  int4 d = *(const int4*)(ei + NEDGE + e4);
  int4 r = *(const int4*)(et + e4);
  int4 p;
  p.x = atomicAdd(&cnt[d.x * NREL + r.x], 1);
  p.y = atomicAdd(&cnt[d.y * NREL + r.y], 1);
  p.z = atomicAdd(&cnt[d.z * NREL + r.z], 1);
  p.w = atomicAdd(&cnt[d.w * NREL + r.w], 1);
  *(int4*)(epos + e4) = p;
}

// --- K2a: per-chunk sums -----------------------------------------------------
__global__ void chunk_sum_kernel(const int* __restrict__ cnt, int* __restrict__ csum) {
  __shared__ int sw[4];
  int t = threadIdx.x, lane = t & 63, wid = t >> 6;
  int i = blockIdx.x * CHUNK + t * 4;
  int s = 0;
  if (i < NBINS) { int4 c = *(const int4*)(cnt + i); s = c.x + c.y + c.z + c.w; }
#pragma unroll
  for (int off = 32; off >= 1; off >>= 1) s += __shfl_xor(s, off);
  if (lane == 0) sw[wid] = s;
  __syncthreads();
  if (t == 0) csum[blockIdx.x] = sw[0] + sw[1] + sw[2] + sw[3];
}

// --- K2b: scan the 391 chunk sums (1 block) ---------------------------------
__global__ void scan_csum_kernel(const int* __restrict__ csum, int* __restrict__ cbase) {
  __shared__ int sw[8];
  int t = threadIdx.x, lane = t & 63, wid = t >> 6;  // 512 threads
  int v0 = (t < NCHUNK) ? csum[t] : 0;
  int v = v0;
#pragma unroll
  for (int off = 1; off < 64; off <<= 1) {
    int u = __shfl_up(v, off);
    if (lane >= off) v += u;
  }
  if (lane == 63) sw[wid] = v;
  __syncthreads();
  if (t == 0) {
    int run = 0;
#pragma unroll
    for (int j = 0; j < 8; ++j) { int x = sw[j]; sw[j] = run; run += x; }
  }
  __syncthreads();
  if (t < NCHUNK) cbase[t] = sw[wid] + (v - v0);
}

// --- K2c: per-chunk exclusive scan + base -> binptr --------------------------
__global__ void scan_write_kernel(const int* __restrict__ cnt, const int* __restrict__ cbase,
                                  int* __restrict__ binptr) {
  __shared__ int sw[4];
  int t = threadIdx.x, lane = t & 63, wid = t >> 6;
  int i = blockIdx.x * CHUNK + t * 4;
  int4 c = make_int4(0, 0, 0, 0);
  if (i < NBINS) c = *(const int4*)(cnt + i);
  int p0 = c.x, p1 = p0 + c.y, p2 = p1 + c.z, s = p2 + c.w;
  int v = s;
#pragma unroll
  for (int off = 1; off < 64; off <<= 1) {
    int u = __shfl_up(v, off);
    if (lane >= off) v += u;
  }
  if (lane == 63) sw[wid] = v;
  __syncthreads();
  if (t == 0) {
    int run = 0;
#pragma unroll
    for (int j = 0; j < 4; ++j) { int x = sw[j]; sw[j] = run; run += x; }
  }
  __syncthreads();
  if (i < NBINS) {
    int excl = cbase[blockIdx.x] + sw[wid] + (v - s);
    *(int4*)(binptr + i) = make_int4(excl, excl + p0, excl + p1, excl + p2);
  }
  if (blockIdx.x == 0 && t == 0) binptr[NBINS] = NEDGE;
}

// --- K3: scatter -> epo[pos] = {rel*NNODES+src, bits(1/cnt)}; 4 edges/thread -
__global__ void scatter_kernel(const int* __restrict__ ei, const int* __restrict__ et,
                               const int* __restrict__ epos, const int* __restrict__ binptr,
                               int2* __restrict__ epo) {
  int e4 = (blockIdx.x * blockDim.x + threadIdx.x) * 4;
  if (e4 >= NEDGE) return;
  int4 sv = *(const int4*)(ei + e4);
  int4 dv = *(const int4*)(ei + NEDGE + e4);
  int4 rv = *(const int4*)(et + e4);
  int4 pv = *(const int4*)(epos + e4);
  int srcs[4] = {sv.x, sv.y, sv.z, sv.w};
  int dsts[4] = {dv.x, dv.y, dv.z, dv.w};
  int rels[4] = {rv.x, rv.y, rv.z, rv.w};
  int poss[4] = {pv.x, pv.y, pv.z, pv.w};
#pragma unroll
  for (int j = 0; j < 4; ++j) {
    int bin = dsts[j] * NREL + rels[j];
    int b = binptr[bin];
    int c = binptr[bin + 1] - b;
    float sc = 1.0f / (float)c;  // c >= 1 (this edge is in the bin)
    epo[b + poss[j]] = make_int2(rels[j] * NNODES + srcs[j], __float_as_int(sc));
  }
}

// --- K4: conv1 — wave per node; 64-edge coalesced batch -> SGPR broadcast;
//         explicit 8-deep load batching keeps 8 gathers in flight ------------
__global__ __launch_bounds__(256) void conv1_kernel(
    const int* __restrict__ binptr, const int2* __restrict__ epo,
    const float* __restrict__ w1, const float* __restrict__ root1,
    const float* __restrict__ bias1, float* __restrict__ h1) {
  int wave = blockIdx.x * 4 + (threadIdx.x >> 6);
  if (wave >= NNODES) return;
  int lane = threadIdx.x & 63;
  int b0 = binptr[wave * NREL], b8 = binptr[wave * NREL + NREL];
  float acc = 0.f;
  for (int eb = b0; eb < b8; eb += 64) {
    int mb = min(64, b8 - eb);
    int2 q = epo[eb + min(lane, mb - 1)];
    int j = 0;
    for (; j + 8 <= mb; j += 8) {
      float a[8], sc[8];
#pragma unroll
      for (int u = 0; u < 8; ++u) {
        int idx = __builtin_amdgcn_readlane(q.x, j + u);
        sc[u] = __int_as_float(__builtin_amdgcn_readlane(q.y, j + u));
        a[u] = w1[(((size_t)(unsigned)idx) << 6) + lane];
      }
#pragma unroll
      for (int u = 0; u < 8; ++u) acc = fmaf(a[u], sc[u], acc);
    }
    for (; j < mb; ++j) {
      int idx = __builtin_amdgcn_readlane(q.x, j);
      float s = __int_as_float(__builtin_amdgcn_readlane(q.y, j));
      acc = fmaf(w1[(((size_t)(unsigned)idx) << 6) + lane], s, acc);
    }
  }
  float v = acc + root1[(wave << 6) + lane] + bias1[lane];
  h1[(wave << 6) + lane] = elu1(v);
}

// --- K5a: conv2 aggregation — wave per (node,rel) bin; 4-deep load batch -----
__global__ __launch_bounds__(256) void conv2a_kernel(
    const int* __restrict__ binptr, const int2* __restrict__ epo,
    const float* __restrict__ h1, float* __restrict__ agg, int nodeBase, int nloc) {
  int wv = blockIdx.x * 4 + (threadIdx.x >> 6);
  if (wv >= nloc * NREL) return;
  int lane = threadIdx.x & 63;
  int r = wv & 7;
  int bin = (nodeBase + (wv >> 3)) * NREL + r;
  int bb = binptr[bin], ee = binptr[bin + 1];
  int rb = r * NNODES;
  float s = 0.f;
  for (int e = bb; e < ee; e += 64) {
    int mb = min(64, ee - e);
    int2 q = epo[e + min(lane, mb - 1)];
    int j = 0;
    for (; j + 4 <= mb; j += 4) {
      float a[4];
#pragma unroll
      for (int u = 0; u < 4; ++u) {
        int i0 = __builtin_amdgcn_readlane(q.x, j + u) - rb;
        a[u] = h1[(((size_t)(unsigned)i0) << 6) + lane];
      }
#pragma unroll
      for (int u = 0; u < 4; ++u) s += a[u];
    }
    for (; j < mb; ++j) {
      int i0 = __builtin_amdgcn_readlane(q.x, j) - rb;
      s += h1[(((size_t)(unsigned)i0) << 6) + lane];
    }
  }
  float out = (ee > bb) ? s * (1.0f / (float)(ee - bb)) : 0.f;
  agg[((size_t)wv << 6) + lane] = out;
}

// --- K5b: conv2 transform — LDS-staged W (16 KB per relation), scalar A ------
__global__ __launch_bounds__(256, 4) void conv2b_kernel(
    const float* __restrict__ agg, const float* __restrict__ h1,
    const float* __restrict__ w2, const float* __restrict__ root2,
    const float* __restrict__ bias2, float* __restrict__ h2, int nodeBase) {
  __shared__ float sW[HID * HID];  // 16 KB
  int t = threadIdx.x, lane = t & 63, wid = t >> 6;
  int ln0 = blockIdx.x * 8 + wid * 2;  // 8 local nodes/block, 2 per wave
  float bz = bias2[lane];
  float o0 = bz, o1 = bz;
  for (int r = 0; r < NREL; ++r) {
    if (r) __syncthreads();
#pragma unroll
    for (int i = 0; i < 4; ++i)
      *(float4*)(sW + t * 4 + i * 1024) = *(const float4*)(w2 + (r << 12) + t * 4 + i * 1024);
    __syncthreads();
    const float* a0 = agg + (((size_t)((ln0 + 0) * NREL + r)) << 6);  // wave-uniform -> s_load
    const float* a1 = agg + (((size_t)((ln0 + 1) * NREL + r)) << 6);
#pragma unroll 16
    for (int k = 0; k < HID; ++k) {
      float w = sW[(k << 6) + lane];
      o0 = fmaf(a0[k], w, o0);
      o1 = fmaf(a1[k], w, o1);
    }
  }
  __syncthreads();
#pragma unroll
  for (int i = 0; i < 4; ++i)
    *(float4*)(sW + t * 4 + i * 1024) = *(const float4*)(root2 + t * 4 + i * 1024);
  __syncthreads();
  int g0 = nodeBase + ln0;
  const float* r0p = h1 + ((size_t)(g0 + 0) << 6);  // wave-uniform -> s_load
  const float* r1p = h1 + ((size_t)(g0 + 1) << 6);
#pragma unroll 16
  for (int k = 0; k < HID; ++k) {
    float w = sW[(k << 6) + lane];
    o0 = fmaf(r0p[k], w, o0);
    o1 = fmaf(r1p[k], w, o1);
  }
  h2[((size_t)(g0 + 0) << 6) + lane] = elu1(o0);
  h2[((size_t)(g0 + 1) << 6) + lane] = elu1(o1);
}

// --- K6: linear head ---------------------------------------------------------
__global__ void head_kernel(const float* __restrict__ h2, const float* __restrict__ lin_w,
                            const float* __restrict__ lin_b, float* __restrict__ out) {
  int t = blockIdx.x * blockDim.x + threadIdx.x;
  if (t >= NTGT * NCLS) return;
  int n = t >> 4, c = t & 15;
  float acc = lin_b[c];
#pragma unroll
  for (int k = 0; k < HID; ++k)
    acc = fmaf(h2[(n << 6) + k], lin_w[k * NCLS + c], acc);
  out[t] = acc;
}

extern "C" void kernel_launch(void* const* d_in, const int* in_sizes, int n_in,
                              void* d_out, int out_size, void* d_ws, size_t ws_size,
                              hipStream_t stream) {
  const int*   ei    = (const int*)d_in[0];
  const int*   et    = (const int*)d_in[1];
  const float* w1    = (const float*)d_in[3];
  const float* root1 = (const float*)d_in[4];
  const float* bias1 = (const float*)d_in[5];
  const float* w2    = (const float*)d_in[6];
  const float* root2 = (const float*)d_in[7];
  const float* bias2 = (const float*)d_in[8];
  const float* lin_w = (const float*)d_in[9];
  const float* lin_b = (const float*)d_in[10];
  float* out = (float*)d_out;

  // Workspace:
  //  A [0,12.8M): cnt(1.6)+epos(6.4) live until scatter; conv1 then writes h1 here
  //  B binptr/csum/cbase; C epo 12.8M; D h2 2.1M; E agg (chunk*8*64*4)
  char* ws = (char*)d_ws;
  float* h1     = (float*)ws;
  int*   cnt    = (int*)ws;
  int*   epos   = (int*)(ws + (size_t)NBINS * 4);
  char*  p      = ws + (size_t)NNODES * HID * 4;
  int*   binptr = (int*)p;  p += ((size_t)(NBINS + 1) * 4 + 255) & ~(size_t)255;
  int*   csum   = (int*)p;  p += ((size_t)NCHUNK * 4 + 255) & ~(size_t)255;
  int*   cbase  = (int*)p;  p += ((size_t)NCHUNK * 4 + 255) & ~(size_t)255;
  int2*  epo    = (int2*)p; p += (size_t)NEDGE * 8;
  float* h2     = (float*)p; p += (size_t)NTGT * HID * 4;
  float* agg    = (float*)p;
  size_t fixed  = (size_t)(p - ws);
  // chunk = 8192 (single conv2 pass) if ws allows, else 4096 (two passes).
  // ws_size is constant across calls -> branch is stable under graph capture.
  int chunk = (fixed + (size_t)NTGT * NREL * HID * 4 <= ws_size) ? NTGT : NTGT / 2;

  hipMemsetAsync(cnt, 0, (size_t)NBINS * sizeof(int), stream);
  count_kernel<<<(NEDGE / 4 + 255) / 256, 256, 0, stream>>>(ei, et, cnt, epos);
  chunk_sum_kernel<<<NCHUNK, 256, 0, stream>>>(cnt, csum);
  scan_csum_kernel<<<1, 512, 0, stream>>>(csum, cbase);
  scan_write_kernel<<<NCHUNK, 256, 0, stream>>>(cnt, cbase, binptr);
  scatter_kernel<<<(NEDGE / 4 + 255) / 256, 256, 0, stream>>>(ei, et, epos, binptr, epo);
  conv1_kernel<<<(NNODES + 3) / 4, 256, 0, stream>>>(binptr, epo, w1, root1, bias1, h1);
  for (int c = 0; c < NTGT / chunk; ++c) {
    conv2a_kernel<<<(chunk * NREL) / 4, 256, 0, stream>>>(binptr, epo, h1, agg, c * chunk, chunk);
    conv2b_kernel<<<chunk / 8, 256, 0, stream>>>(agg, h1, w2, root2, bias2, h2, c * chunk);
  }
  head_kernel<<<(NTGT * NCLS + 255) / 256, 256, 0, stream>>>(h2, lin_w, lin_b, out);
}